// Round 7
// baseline (233.422 us; speedup 1.0000x reference)
//
#include <hip/hip_runtime.h>

#define NN 50000
#define NNP 50016   // 1563 * 32, padded rows for the GEMM
#define NE 800000
#define DIN 64
#define HD 128
#define NBUK 196            // ceil(NN/256) coarse buckets (dst>>8)
#define SB 196              // ceil(NE/4096) scatter chunks
#define BCAP 12288          // build_csr LDS capacity (edges per bucket fast path)

typedef __attribute__((ext_vector_type(8))) short short8;
typedef __attribute__((ext_vector_type(4))) float f32x4;
typedef __attribute__((ext_vector_type(4))) unsigned short us4;
typedef __attribute__((ext_vector_type(8))) unsigned short us8;

__device__ __forceinline__ unsigned short f2bf(float f) {
    unsigned int u = __float_as_uint(f);
    u = (u + 0x7FFFu + ((u >> 16) & 1u)) >> 16;
    return (unsigned short)u;
}
__device__ __forceinline__ float bf2f(unsigned short u) {
    return __uint_as_float(((unsigned int)u) << 16);
}

// inclusive Hillis-Steele scan over a[256]; all 256 threads must execute
#define LDS_SCAN256(a, t)                                 \
    for (int off_ = 1; off_ < 256; off_ <<= 1) {          \
        int add_ = ((t) >= off_) ? (a)[(t) - off_] : 0;   \
        __syncthreads();                                  \
        (a)[t] += add_;                                   \
        __syncthreads();                                  \
    }

// ---------------- CSR via two-level LDS counting sort ----------------

__global__ void zero_meta(int* __restrict__ meta) {
    meta[threadIdx.x] = 0;  // 512 threads: bcnt[256] + bfill[256]
}

__global__ __launch_bounds__(256) void bucket_count(const int* __restrict__ dst,
                                                    int* __restrict__ bcnt) {
    __shared__ int lc[256];
    int t = threadIdx.x;
    lc[t] = 0;
    __syncthreads();
    int base = blockIdx.x * 4096 + t * 16;
#pragma unroll
    for (int j = 0; j < 4; ++j) {
        int e = base + j * 4;
        if (e < NE) {
            int4 d = *(const int4*)(dst + e);
            atomicAdd(&lc[d.x >> 8], 1);
            atomicAdd(&lc[d.y >> 8], 1);
            atomicAdd(&lc[d.z >> 8], 1);
            atomicAdd(&lc[d.w >> 8], 1);
        }
    }
    __syncthreads();
    if (t < NBUK && lc[t] > 0) atomicAdd(&bcnt[t], lc[t]);
}

__global__ __launch_bounds__(256) void bucket_scan(const int* __restrict__ bcnt,
                                                   int* __restrict__ bbase,
                                                   int* __restrict__ rowptr) {
    __shared__ int sh[256];
    int t = threadIdx.x;
    int v = (t < NBUK) ? bcnt[t] : 0;
    sh[t] = v;
    __syncthreads();
    LDS_SCAN256(sh, t);
    if (t < NBUK) bbase[t] = sh[t] - v;   // exclusive
    if (t == NBUK - 1) bbase[NBUK] = sh[t];
    if (t == 0) rowptr[NN] = NE;
}

__global__ __launch_bounds__(256) void bucket_scatter(
    const int* __restrict__ src, const int* __restrict__ dst,
    const int* __restrict__ bbase, int* __restrict__ bfill,
    int2* __restrict__ pairs) {
    __shared__ int cnt[256];
    __shared__ int incl[256];
    __shared__ int lfill[256];
    __shared__ int rung[256];
    __shared__ int2 buf[4096];
    int t = threadIdx.x;
    cnt[t] = 0;
    lfill[t] = 0;
    __syncthreads();
    int base = blockIdx.x * 4096 + t * 16;
    // phase A: local bucket histogram
#pragma unroll
    for (int j = 0; j < 4; ++j) {
        int e = base + j * 4;
        if (e < NE) {
            int4 d = *(const int4*)(dst + e);
            atomicAdd(&cnt[d.x >> 8], 1);
            atomicAdd(&cnt[d.y >> 8], 1);
            atomicAdd(&cnt[d.z >> 8], 1);
            atomicAdd(&cnt[d.w >> 8], 1);
        }
    }
    __syncthreads();
    incl[t] = cnt[t];
    __syncthreads();
    LDS_SCAN256(incl, t);
    // phase B: allocate one global run per non-empty bucket
    int c = cnt[t];
    if (t < NBUK && c > 0) rung[t] = bbase[t] + atomicAdd(&bfill[t], c);
    __syncthreads();
    // phase C: local scatter into LDS, grouped by bucket
#pragma unroll
    for (int j = 0; j < 4; ++j) {
        int e = base + j * 4;
        if (e < NE) {
            int4 s4 = *(const int4*)(src + e);
            int4 d4 = *(const int4*)(dst + e);
            int ss[4] = {s4.x, s4.y, s4.z, s4.w};
            int dd[4] = {d4.x, d4.y, d4.z, d4.w};
#pragma unroll
            for (int q = 0; q < 4; ++q) {
                int k = dd[q] >> 8;
                int p = (incl[k] - cnt[k]) + atomicAdd(&lfill[k], 1);
                buf[p] = {ss[q], dd[q]};
            }
        }
    }
    __syncthreads();
    // phase D: coalesced run writes
    int n = min(4096, NE - blockIdx.x * 4096);
    for (int i = t; i < n; i += 256) {
        int2 pr = buf[i];
        int k = pr.y >> 8;
        pairs[rung[k] + (i - (incl[k] - cnt[k]))] = pr;
    }
}

__global__ __launch_bounds__(256) void build_csr(
    const int2* __restrict__ pairs, const int* __restrict__ bbase,
    int* __restrict__ rowptr, float* __restrict__ invcnt,
    int* __restrict__ csr_src) {
    __shared__ int cnt[256];
    __shared__ int incl[256];
    __shared__ int lfill[256];
    __shared__ int sbuf[BCAP];
    int b = blockIdx.x, t = threadIdx.x;
    int pbeg = bbase[b], pend = bbase[b + 1];
    int sz = pend - pbeg;
    cnt[t] = 0;
    lfill[t] = 0;
    __syncthreads();
    for (int i = t; i < sz; i += 256)
        atomicAdd(&cnt[pairs[pbeg + i].y & 255], 1);
    __syncthreads();
    incl[t] = cnt[t];
    __syncthreads();
    LDS_SCAN256(incl, t);
    int node = b * 256 + t;
    int c = cnt[t];
    if (node < NN) {
        rowptr[node] = pbeg + incl[t] - c;   // global exclusive position
        invcnt[node] = 1.0f / (float)(c > 0 ? c : 1);
    }
    if (sz <= BCAP) {
        for (int i = t; i < sz; i += 256) {
            int2 pr = pairs[pbeg + i];
            int ld = pr.y & 255;
            sbuf[(incl[ld] - cnt[ld]) + atomicAdd(&lfill[ld], 1)] = pr.x;
        }
        __syncthreads();
        for (int i = t; i < sz; i += 256) csr_src[pbeg + i] = sbuf[i];
    } else {  // safety fallback (not hit for uniform dst)
        for (int i = t; i < sz; i += 256) {
            int2 pr = pairs[pbeg + i];
            int ld = pr.y & 255;
            csr_src[pbeg + (incl[ld] - cnt[ld]) + atomicAdd(&lfill[ld], 1)] = pr.x;
        }
    }
}

// ---------------- prep: pack weights into MFMA B-fragment order (bf16) ----------------

__device__ __forceinline__ void pack_one(const float* Wl, const float* Wr, int D,
                                         unsigned short* Wpk, int i) {
    int j = i & 7;
    int lane = (i >> 3) & 63;
    int ct = (i >> 9) & 7;
    int ks = i >> 12;
    int k = ks * 32 + ((lane >> 4) << 3) + j;
    int c = ct * 16 + (lane & 15);
    float v = (k < D) ? Wl[c * D + k] : Wr[c * D + (k - D)];
    Wpk[i] = f2bf(v);
}

__global__ void pack_weights(const float* __restrict__ Wl0, const float* __restrict__ Wr0,
                             const float* __restrict__ Wl1, const float* __restrict__ Wr1,
                             const float* __restrict__ Wl2, const float* __restrict__ Wr2,
                             unsigned short* __restrict__ Wpk0,
                             unsigned short* __restrict__ Wpk1,
                             unsigned short* __restrict__ Wpk2) {
    const int S0 = 2 * DIN * HD;   // 16384
    const int S12 = 2 * HD * HD;   // 32768
    int i = blockIdx.x * blockDim.x + threadIdx.x;
    if (i < S0) { pack_one(Wl0, Wr0, DIN, Wpk0, i); return; }
    int j = i - S0;
    if (j < S12) { pack_one(Wl1, Wr1, HD, Wpk1, j); return; }
    int m = j - S12;
    if (m < S12) pack_one(Wl2, Wr2, HD, Wpk2, m);
}

// x f32 [NN][64] -> bf16 into A0[:, 64:128] (row stride 128 shorts; h-half = one 128B line)
__global__ void conv_x(const float* __restrict__ x, unsigned short* __restrict__ A0) {
    int i = blockIdx.x * blockDim.x + threadIdx.x;  // NN*16 chunks
    if (i >= NN * 16) return;
    int row = i >> 4, c4 = i & 15;
    float4 v = ((const float4*)(x + (size_t)row * DIN))[c4];
    us4 o = {f2bf(v.x), f2bf(v.y), f2bf(v.z), f2bf(v.w)};
    *(us4*)(A0 + (size_t)row * 128 + 64 + c4 * 4) = o;
}

// ---------------- gather-mean layer 0: bf16 x rows (A0 h-half) -> bf16 mean (A0[:,0:64]) ----------------
// 128 threads: 16 edge-groups x 8 lanes (us8 = 64ch); tree reduce in padded LDS.

__global__ void gather_mean_x(const int* __restrict__ rowptr, const int* __restrict__ csr_src,
                              const float* __restrict__ invcnt, unsigned short* __restrict__ A0) {
    __shared__ float red[128][9];
    int n = blockIdx.x, t = threadIdx.x;
    int c8 = t & 7;    // 8 lanes x 8ch = 64
    int g = t >> 3;    // 16 groups
    int beg = rowptr[n], end = rowptr[n + 1];
    float acc[8] = {};
    const unsigned short* hb = A0 + 64 + (size_t)c8 * 8;
    for (int e = beg + g; e < end; e += 16) {
        us8 v = *(const us8*)(hb + (size_t)csr_src[e] * 128);
#pragma unroll
        for (int j = 0; j < 8; ++j) acc[j] += bf2f(v[j]);
    }
#pragma unroll
    for (int j = 0; j < 8; ++j) red[t][j] = acc[j];
    __syncthreads();
    if (t < 64) {
#pragma unroll
        for (int j = 0; j < 8; ++j) red[t][j] += red[t + 64][j];
    }
    __syncthreads();
    if (t < 32) {
#pragma unroll
        for (int j = 0; j < 8; ++j) red[t][j] += red[t + 32][j];
    }
    __syncthreads();
    if (t < 16) {
#pragma unroll
        for (int j = 0; j < 8; ++j) red[t][j] += red[t + 16][j];
    }
    __syncthreads();
    if (t < 8) {
        float ic = invcnt[n];
        us8 o;
#pragma unroll
        for (int j = 0; j < 8; ++j) o[j] = f2bf((red[t][j] + red[t + 8][j]) * ic);
        *(us8*)(A0 + (size_t)n * 128 + t * 8) = o;
    }
}

// ---------------- gather-mean layers 1,2: bf16 h in (A12[:,128:256]), bf16 mean out ----------------
// 256 threads: 16 edge-groups x 16 lanes (us8 = 128ch); tree reduce in padded LDS.

__global__ __launch_bounds__(256) void gather_mean_h(
    const unsigned short* __restrict__ A12, const int* __restrict__ rowptr,
    const int* __restrict__ csr_src, const float* __restrict__ invcnt,
    unsigned short* __restrict__ Am) {
    __shared__ float red[256][9];
    int n = blockIdx.x, t = threadIdx.x;
    int c8 = t & 15;   // 16 lanes x 8ch = 128
    int g = t >> 4;    // 16 groups
    int beg = rowptr[n], end = rowptr[n + 1];
    float acc[8] = {};
    const unsigned short* hb = A12 + 128 + (size_t)c8 * 8;
    for (int e = beg + g; e < end; e += 16) {
        us8 v = *(const us8*)(hb + (size_t)csr_src[e] * 256);
#pragma unroll
        for (int j = 0; j < 8; ++j) acc[j] += bf2f(v[j]);
    }
#pragma unroll
    for (int j = 0; j < 8; ++j) red[t][j] = acc[j];
    __syncthreads();
    if (t < 128) {
#pragma unroll
        for (int j = 0; j < 8; ++j) red[t][j] += red[t + 128][j];
    }
    __syncthreads();
    if (t < 64) {
#pragma unroll
        for (int j = 0; j < 8; ++j) red[t][j] += red[t + 64][j];
    }
    __syncthreads();
    if (t < 32) {
#pragma unroll
        for (int j = 0; j < 8; ++j) red[t][j] += red[t + 32][j];
    }
    __syncthreads();
    if (t < 16) {
        float ic = invcnt[n];
        us8 o;
#pragma unroll
        for (int j = 0; j < 8; ++j) o[j] = f2bf((red[t][j] + red[t + 16][j]) * ic);
        *(us8*)(Am + (size_t)n * 256 + t * 8) = o;
    }
}

// ---------------- fused MFMA GEMM + bias + L2 norm + (ReLU) ----------------

template <int K, bool RELU, bool F32OUT, bool BF16H>
__global__ __launch_bounds__(256) void linear_mfma(
    const unsigned short* __restrict__ A, const unsigned short* __restrict__ Wpk,
    const float* __restrict__ bias, float* __restrict__ outF,
    unsigned short* __restrict__ Hn /* h-part base (stride 256) */) {
    constexpr int NK = K / 32;
    __shared__ float rsum[2][32];
    int tid = threadIdx.x;
    int lane = tid & 63, w = tid >> 6;
    int rg = w >> 1, cg = w & 1;
    int r0 = blockIdx.x * 32 + rg * 16;
    int row_l = lane & 15, kb = lane >> 4;

    const unsigned short* Arow = A + (size_t)(r0 + row_l) * K + kb * 8;
    const unsigned short* Wp = Wpk + ((size_t)(cg * 4) * 64 + lane) * 8;

    f32x4 acc[4] = {{0.f, 0.f, 0.f, 0.f}, {0.f, 0.f, 0.f, 0.f},
                    {0.f, 0.f, 0.f, 0.f}, {0.f, 0.f, 0.f, 0.f}};
#pragma unroll
    for (int ks = 0; ks < NK; ++ks) {
        short8 a = *(const short8*)(Arow + ks * 32);
#pragma unroll
        for (int t = 0; t < 4; ++t) {
            short8 b = *(const short8*)(Wp + ((size_t)ks * 8 + t) * 64 * 8);
            acc[t] = __builtin_amdgcn_mfma_f32_16x16x32_bf16(a, b, acc[t], 0, 0, 0);
        }
    }

    float sq[4] = {0.f, 0.f, 0.f, 0.f};
#pragma unroll
    for (int t = 0; t < 4; ++t) {
        float bv = bias[cg * 64 + t * 16 + row_l];
#pragma unroll
        for (int r = 0; r < 4; ++r) {
            acc[t][r] += bv;
            sq[r] = fmaf(acc[t][r], acc[t][r], sq[r]);
        }
    }
#pragma unroll
    for (int off = 1; off < 16; off <<= 1)
#pragma unroll
        for (int r = 0; r < 4; ++r) sq[r] += __shfl_xor(sq[r], off, 64);

    if (row_l == 0) {
#pragma unroll
        for (int r = 0; r < 4; ++r) rsum[cg][rg * 16 + kb * 4 + r] = sq[r];
    }
    __syncthreads();  // also orders all A reads before the BF16H in-place writes

    int rbase = rg * 16 + kb * 4;
#pragma unroll
    for (int r = 0; r < 4; ++r) {
        int row = r0 + kb * 4 + r;
        if (row >= NN) continue;
        float n2 = rsum[0][rbase + r] + rsum[1][rbase + r];
        float inv = 1.0f / fmaxf(sqrtf(n2), 1e-12f);
#pragma unroll
        for (int t = 0; t < 4; ++t) {
            float v = acc[t][r] * inv;
            if (RELU) v = fmaxf(v, 0.f);
            int c = cg * 64 + t * 16 + row_l;
            if (F32OUT) outF[(size_t)row * HD + c] = v;
            if (BF16H) Hn[(size_t)row * 256 + c] = f2bf(v);
        }
    }
}

// ---------------- launch ----------------

static inline size_t align256(size_t x) { return (x + 255) & ~(size_t)255; }

extern "C" void kernel_launch(void* const* d_in, const int* in_sizes, int n_in,
                              void* d_out, int out_size, void* d_ws, size_t ws_size,
                              hipStream_t stream) {
    const float* x   = (const float*)d_in[0];
    const int*   ei  = (const int*)d_in[1];
    const float* Wl0 = (const float*)d_in[2];
    const float* bl0 = (const float*)d_in[3];
    const float* Wr0 = (const float*)d_in[4];
    const float* Wl1 = (const float*)d_in[5];
    const float* bl1 = (const float*)d_in[6];
    const float* Wr1 = (const float*)d_in[7];
    const float* Wl2 = (const float*)d_in[8];
    const float* bl2 = (const float*)d_in[9];
    const float* Wr2 = (const float*)d_in[10];

    const int* src = ei;
    const int* dst = ei + NE;

    // workspace carve-up
    char* p = (char*)d_ws;
    size_t off = 0;
    int* meta = (int*)(p + off);            off = align256(off + 512 * 4);  // bcnt[256]+bfill[256]
    int* bbase = (int*)(p + off);           off = align256(off + 256 * 4);
    int* rowptr = (int*)(p + off);          off = align256(off + (size_t)(NN + 1) * 4);
    int* csr_src = (int*)(p + off);         off = align256(off + (size_t)NE * 4);
    float* invcnt = (float*)(p + off);      off = align256(off + (size_t)NN * 4);
    int2* pairs = (int2*)(p + off);         off = align256(off + (size_t)NE * 8);
    unsigned short* A0 = (unsigned short*)(p + off);   off = align256(off + (size_t)NNP * 128 * 2);
    unsigned short* A12 = (unsigned short*)(p + off);  off = align256(off + (size_t)NNP * 256 * 2);
    unsigned short* Wpk0 = (unsigned short*)(p + off); off = align256(off + (size_t)2 * DIN * HD * 2);
    unsigned short* Wpk1 = (unsigned short*)(p + off); off = align256(off + (size_t)2 * HD * HD * 2);
    unsigned short* Wpk2 = (unsigned short*)(p + off); off = align256(off + (size_t)2 * HD * HD * 2);
    (void)ws_size; (void)n_in; (void)in_sizes; (void)out_size;

    int* bcnt = meta;
    int* bfill = meta + 256;
    float* out = (float*)d_out;

    // CSR build: two-level LDS counting sort (coalesced writes, no cross-XCD line sharing)
    zero_meta<<<1, 512, 0, stream>>>(meta);
    bucket_count<<<SB, 256, 0, stream>>>(dst, bcnt);
    bucket_scan<<<1, 256, 0, stream>>>(bcnt, bbase, rowptr);
    bucket_scatter<<<SB, 256, 0, stream>>>(src, dst, bbase, bfill, pairs);
    build_csr<<<NBUK, 256, 0, stream>>>(pairs, bbase, rowptr, invcnt, csr_src);

    // prep (independent of CSR): packed weights + dense x->bf16 into A0 h-half
    const int WTOT = 2 * DIN * HD + 2 * 2 * HD * HD;  // 81920
    pack_weights<<<(WTOT + 255) / 256, 256, 0, stream>>>(Wl0, Wr0, Wl1, Wr1, Wl2, Wr2,
                                                         Wpk0, Wpk1, Wpk2);
    conv_x<<<(NN * 16 + 255) / 256, 256, 0, stream>>>(x, A0);

    const int LG = NNP / 32;  // 1563

    // layer 0: gather bf16 x rows -> A0 mean part; GEMM K=128 -> h0 bf16 into A12[:,128:256]
    gather_mean_x<<<NN, 128, 0, stream>>>(rowptr, csr_src, invcnt, A0);
    linear_mfma<2 * DIN, true, false, true><<<LG, 256, 0, stream>>>(
        A0, Wpk0, bl0, nullptr, A12 + 128);

    // layer 1: gather h0 (bf16) -> A12 mean part; GEMM K=256 -> h1 bf16 (in place)
    gather_mean_h<<<NN, 256, 0, stream>>>(A12, rowptr, csr_src, invcnt, A12);
    linear_mfma<2 * HD, true, false, true><<<LG, 256, 0, stream>>>(
        A12, Wpk1, bl1, nullptr, A12 + 128);

    // layer 2: gather h1 -> A12 mean part; GEMM K=256 -> f32 d_out
    gather_mean_h<<<NN, 256, 0, stream>>>(A12, rowptr, csr_src, invcnt, A12);
    linear_mfma<2 * HD, false, true, false><<<LG, 256, 0, stream>>>(
        A12, Wpk2, bl2, out, nullptr);
}

// Round 8
// 176.022 us; speedup vs baseline: 1.3261x; 1.3261x over previous
//
#include <hip/hip_runtime.h>

#define NN 50000
#define NNP 50016   // 1563 * 32, padded rows for the GEMM
#define NE 800000
#define DIN 64
#define HD 128
#define NBUK 196            // ceil(NN/256) coarse buckets (dst>>8)
#define SB 196              // ceil(NE/4096) scatter chunks
#define BCAP 12288          // build_csr LDS capacity (edges per bucket fast path)

typedef __attribute__((ext_vector_type(8))) short short8;
typedef __attribute__((ext_vector_type(4))) float f32x4;
typedef __attribute__((ext_vector_type(4))) unsigned short us4;
typedef __attribute__((ext_vector_type(8))) unsigned short us8;

__device__ __forceinline__ unsigned short f2bf(float f) {
    unsigned int u = __float_as_uint(f);
    u = (u + 0x7FFFu + ((u >> 16) & 1u)) >> 16;
    return (unsigned short)u;
}
__device__ __forceinline__ float bf2f(unsigned short u) {
    return __uint_as_float(((unsigned int)u) << 16);
}

// inclusive Hillis-Steele scan over a[256]; all 256 threads must execute
#define LDS_SCAN256(a, t)                                 \
    for (int off_ = 1; off_ < 256; off_ <<= 1) {          \
        int add_ = ((t) >= off_) ? (a)[(t) - off_] : 0;   \
        __syncthreads();                                  \
        (a)[t] += add_;                                   \
        __syncthreads();                                  \
    }

// ---------------- CSR via two-level LDS counting sort ----------------

__global__ void zero_meta(int* __restrict__ meta) {
    meta[threadIdx.x] = 0;  // 512 threads: bcnt[256] + bfill[256]
}

__global__ __launch_bounds__(256) void bucket_count(const int* __restrict__ dst,
                                                    int* __restrict__ bcnt) {
    __shared__ int lc[256];
    int t = threadIdx.x;
    lc[t] = 0;
    __syncthreads();
    int base = blockIdx.x * 4096 + t * 16;
#pragma unroll
    for (int j = 0; j < 4; ++j) {
        int e = base + j * 4;
        if (e < NE) {
            int4 d = *(const int4*)(dst + e);
            atomicAdd(&lc[d.x >> 8], 1);
            atomicAdd(&lc[d.y >> 8], 1);
            atomicAdd(&lc[d.z >> 8], 1);
            atomicAdd(&lc[d.w >> 8], 1);
        }
    }
    __syncthreads();
    if (t < NBUK && lc[t] > 0) atomicAdd(&bcnt[t], lc[t]);
}

__global__ __launch_bounds__(256) void bucket_scan(const int* __restrict__ bcnt,
                                                   int* __restrict__ bbase,
                                                   int* __restrict__ rowptr) {
    __shared__ int sh[256];
    int t = threadIdx.x;
    int v = (t < NBUK) ? bcnt[t] : 0;
    sh[t] = v;
    __syncthreads();
    LDS_SCAN256(sh, t);
    if (t < NBUK) bbase[t] = sh[t] - v;   // exclusive
    if (t == NBUK - 1) bbase[NBUK] = sh[t];
    if (t == 0) rowptr[NN] = NE;
}

__global__ __launch_bounds__(256) void bucket_scatter(
    const int* __restrict__ src, const int* __restrict__ dst,
    const int* __restrict__ bbase, int* __restrict__ bfill,
    int2* __restrict__ pairs) {
    __shared__ int cnt[256];
    __shared__ int incl[256];
    __shared__ int lfill[256];
    __shared__ int rung[256];
    __shared__ int2 buf[4096];
    int t = threadIdx.x;
    cnt[t] = 0;
    lfill[t] = 0;
    __syncthreads();
    int base = blockIdx.x * 4096 + t * 16;
    // phase A: local bucket histogram
#pragma unroll
    for (int j = 0; j < 4; ++j) {
        int e = base + j * 4;
        if (e < NE) {
            int4 d = *(const int4*)(dst + e);
            atomicAdd(&cnt[d.x >> 8], 1);
            atomicAdd(&cnt[d.y >> 8], 1);
            atomicAdd(&cnt[d.z >> 8], 1);
            atomicAdd(&cnt[d.w >> 8], 1);
        }
    }
    __syncthreads();
    incl[t] = cnt[t];
    __syncthreads();
    LDS_SCAN256(incl, t);
    // phase B: allocate one global run per non-empty bucket
    int c = cnt[t];
    if (t < NBUK && c > 0) rung[t] = bbase[t] + atomicAdd(&bfill[t], c);
    __syncthreads();
    // phase C: local scatter into LDS, grouped by bucket
#pragma unroll
    for (int j = 0; j < 4; ++j) {
        int e = base + j * 4;
        if (e < NE) {
            int4 s4 = *(const int4*)(src + e);
            int4 d4 = *(const int4*)(dst + e);
            int ss[4] = {s4.x, s4.y, s4.z, s4.w};
            int dd[4] = {d4.x, d4.y, d4.z, d4.w};
#pragma unroll
            for (int q = 0; q < 4; ++q) {
                int k = dd[q] >> 8;
                int p = (incl[k] - cnt[k]) + atomicAdd(&lfill[k], 1);
                buf[p] = {ss[q], dd[q]};
            }
        }
    }
    __syncthreads();
    // phase D: coalesced run writes
    int n = min(4096, NE - blockIdx.x * 4096);
    for (int i = t; i < n; i += 256) {
        int2 pr = buf[i];
        int k = pr.y >> 8;
        pairs[rung[k] + (i - (incl[k] - cnt[k]))] = pr;
    }
}

__global__ __launch_bounds__(256) void build_csr(
    const int2* __restrict__ pairs, const int* __restrict__ bbase,
    int* __restrict__ rowptr, float* __restrict__ invcnt,
    int* __restrict__ csr_src) {
    __shared__ int cnt[256];
    __shared__ int incl[256];
    __shared__ int lfill[256];
    __shared__ int sbuf[BCAP];
    int b = blockIdx.x, t = threadIdx.x;
    int pbeg = bbase[b], pend = bbase[b + 1];
    int sz = pend - pbeg;
    cnt[t] = 0;
    lfill[t] = 0;
    __syncthreads();
    for (int i = t; i < sz; i += 256)
        atomicAdd(&cnt[pairs[pbeg + i].y & 255], 1);
    __syncthreads();
    incl[t] = cnt[t];
    __syncthreads();
    LDS_SCAN256(incl, t);
    int node = b * 256 + t;
    int c = cnt[t];
    if (node < NN) {
        rowptr[node] = pbeg + incl[t] - c;   // global exclusive position
        invcnt[node] = 1.0f / (float)(c > 0 ? c : 1);
    }
    if (sz <= BCAP) {
        for (int i = t; i < sz; i += 256) {
            int2 pr = pairs[pbeg + i];
            int ld = pr.y & 255;
            sbuf[(incl[ld] - cnt[ld]) + atomicAdd(&lfill[ld], 1)] = pr.x;
        }
        __syncthreads();
        for (int i = t; i < sz; i += 256) csr_src[pbeg + i] = sbuf[i];
    } else {  // safety fallback (not hit for uniform dst)
        for (int i = t; i < sz; i += 256) {
            int2 pr = pairs[pbeg + i];
            int ld = pr.y & 255;
            csr_src[pbeg + (incl[ld] - cnt[ld]) + atomicAdd(&lfill[ld], 1)] = pr.x;
        }
    }
}

// ---------------- prep: pack weights into MFMA B-fragment order (bf16) ----------------

__device__ __forceinline__ void pack_one(const float* Wl, const float* Wr, int D,
                                         unsigned short* Wpk, int i) {
    int j = i & 7;
    int lane = (i >> 3) & 63;
    int ct = (i >> 9) & 7;
    int ks = i >> 12;
    int k = ks * 32 + ((lane >> 4) << 3) + j;
    int c = ct * 16 + (lane & 15);
    float v = (k < D) ? Wl[c * D + k] : Wr[c * D + (k - D)];
    Wpk[i] = f2bf(v);
}

__global__ void pack_weights(const float* __restrict__ Wl0, const float* __restrict__ Wr0,
                             const float* __restrict__ Wl1, const float* __restrict__ Wr1,
                             const float* __restrict__ Wl2, const float* __restrict__ Wr2,
                             unsigned short* __restrict__ Wpk0,
                             unsigned short* __restrict__ Wpk1,
                             unsigned short* __restrict__ Wpk2) {
    const int S0 = 2 * DIN * HD;   // 16384
    const int S12 = 2 * HD * HD;   // 32768
    int i = blockIdx.x * blockDim.x + threadIdx.x;
    if (i < S0) { pack_one(Wl0, Wr0, DIN, Wpk0, i); return; }
    int j = i - S0;
    if (j < S12) { pack_one(Wl1, Wr1, HD, Wpk1, j); return; }
    int m = j - S12;
    if (m < S12) pack_one(Wl2, Wr2, HD, Wpk2, m);
}

// x f32 [NN][64] -> bf16 into A0[:, 64:128] (row stride 128 shorts; h-half = one 128B line)
__global__ void conv_x(const float* __restrict__ x, unsigned short* __restrict__ A0) {
    int i = blockIdx.x * blockDim.x + threadIdx.x;  // NN*16 chunks
    if (i >= NN * 16) return;
    int row = i >> 4, c4 = i & 15;
    float4 v = ((const float4*)(x + (size_t)row * DIN))[c4];
    us4 o = {f2bf(v.x), f2bf(v.y), f2bf(v.z), f2bf(v.w)};
    *(us4*)(A0 + (size_t)row * 128 + 64 + c4 * 4) = o;
}

// ---------------- gather-mean layer 0: one wave per node, shuffle reduce ----------------
// 8 edge-groups x 8 lanes (us8 = 64ch); 4 nodes per 256-thread block.

__global__ __launch_bounds__(256) void gather_mean_x(
    const int* __restrict__ rowptr, const int* __restrict__ csr_src,
    const float* __restrict__ invcnt, unsigned short* __restrict__ A0) {
    int tid = threadIdx.x;
    int n = blockIdx.x * 4 + (tid >> 6);
    int lane = tid & 63;
    int c8 = lane & 7;    // 8 lanes x 8ch = 64
    int g = lane >> 3;    // 8 edge groups
    int beg = rowptr[n], end = rowptr[n + 1];
    float acc[8] = {};
    const unsigned short* hb = A0 + 64 + (size_t)c8 * 8;
    int e = beg + g;
    for (; e + 8 < end; e += 16) {  // 2-deep load pipeline
        int s0 = csr_src[e], s1 = csr_src[e + 8];
        us8 v0 = *(const us8*)(hb + (size_t)s0 * 128);
        us8 v1 = *(const us8*)(hb + (size_t)s1 * 128);
#pragma unroll
        for (int j = 0; j < 8; ++j) acc[j] += bf2f(v0[j]) + bf2f(v1[j]);
    }
    if (e < end) {
        us8 v0 = *(const us8*)(hb + (size_t)csr_src[e] * 128);
#pragma unroll
        for (int j = 0; j < 8; ++j) acc[j] += bf2f(v0[j]);
    }
#pragma unroll
    for (int j = 0; j < 8; ++j) {
        acc[j] += __shfl_xor(acc[j], 8, 64);
        acc[j] += __shfl_xor(acc[j], 16, 64);
        acc[j] += __shfl_xor(acc[j], 32, 64);
    }
    if (g == 0) {
        float ic = invcnt[n];
        us8 o;
#pragma unroll
        for (int j = 0; j < 8; ++j) o[j] = f2bf(acc[j] * ic);
        *(us8*)(A0 + (size_t)n * 128 + c8 * 8) = o;
    }
}

// ---------------- gather-mean layers 1,2: one wave per node, shuffle reduce ----------------
// 4 edge-groups x 16 lanes (us8 = 128ch); 4 nodes per 256-thread block.

__global__ __launch_bounds__(256) void gather_mean_h(
    const unsigned short* __restrict__ A12, const int* __restrict__ rowptr,
    const int* __restrict__ csr_src, const float* __restrict__ invcnt,
    unsigned short* __restrict__ Am) {
    int tid = threadIdx.x;
    int n = blockIdx.x * 4 + (tid >> 6);
    int lane = tid & 63;
    int c8 = lane & 15;   // 16 lanes x 8ch = 128
    int g = lane >> 4;    // 4 edge groups
    int beg = rowptr[n], end = rowptr[n + 1];
    float acc[8] = {};
    const unsigned short* hb = A12 + 128 + (size_t)c8 * 8;
    int e = beg + g;
    for (; e + 4 < end; e += 8) {  // 2-deep load pipeline
        int s0 = csr_src[e], s1 = csr_src[e + 4];
        us8 v0 = *(const us8*)(hb + (size_t)s0 * 256);
        us8 v1 = *(const us8*)(hb + (size_t)s1 * 256);
#pragma unroll
        for (int j = 0; j < 8; ++j) acc[j] += bf2f(v0[j]) + bf2f(v1[j]);
    }
    if (e < end) {
        us8 v0 = *(const us8*)(hb + (size_t)csr_src[e] * 256);
#pragma unroll
        for (int j = 0; j < 8; ++j) acc[j] += bf2f(v0[j]);
    }
#pragma unroll
    for (int j = 0; j < 8; ++j) {
        acc[j] += __shfl_xor(acc[j], 16, 64);
        acc[j] += __shfl_xor(acc[j], 32, 64);
    }
    if (g == 0) {
        float ic = invcnt[n];
        us8 o;
#pragma unroll
        for (int j = 0; j < 8; ++j) o[j] = f2bf(acc[j] * ic);
        *(us8*)(Am + (size_t)n * 256 + c8 * 8) = o;
    }
}

// ---------------- fused MFMA GEMM + bias + L2 norm + (ReLU) ----------------

template <int K, bool RELU, bool F32OUT, bool BF16H>
__global__ __launch_bounds__(256) void linear_mfma(
    const unsigned short* __restrict__ A, const unsigned short* __restrict__ Wpk,
    const float* __restrict__ bias, float* __restrict__ outF,
    unsigned short* __restrict__ Hn /* h-part base (stride 256) */) {
    constexpr int NK = K / 32;
    __shared__ float rsum[2][32];
    int tid = threadIdx.x;
    int lane = tid & 63, w = tid >> 6;
    int rg = w >> 1, cg = w & 1;
    int r0 = blockIdx.x * 32 + rg * 16;
    int row_l = lane & 15, kb = lane >> 4;

    const unsigned short* Arow = A + (size_t)(r0 + row_l) * K + kb * 8;
    const unsigned short* Wp = Wpk + ((size_t)(cg * 4) * 64 + lane) * 8;

    f32x4 acc[4] = {{0.f, 0.f, 0.f, 0.f}, {0.f, 0.f, 0.f, 0.f},
                    {0.f, 0.f, 0.f, 0.f}, {0.f, 0.f, 0.f, 0.f}};
#pragma unroll
    for (int ks = 0; ks < NK; ++ks) {
        short8 a = *(const short8*)(Arow + ks * 32);
#pragma unroll
        for (int t = 0; t < 4; ++t) {
            short8 b = *(const short8*)(Wp + ((size_t)ks * 8 + t) * 64 * 8);
            acc[t] = __builtin_amdgcn_mfma_f32_16x16x32_bf16(a, b, acc[t], 0, 0, 0);
        }
    }

    float sq[4] = {0.f, 0.f, 0.f, 0.f};
#pragma unroll
    for (int t = 0; t < 4; ++t) {
        float bv = bias[cg * 64 + t * 16 + row_l];
#pragma unroll
        for (int r = 0; r < 4; ++r) {
            acc[t][r] += bv;
            sq[r] = fmaf(acc[t][r], acc[t][r], sq[r]);
        }
    }
#pragma unroll
    for (int off = 1; off < 16; off <<= 1)
#pragma unroll
        for (int r = 0; r < 4; ++r) sq[r] += __shfl_xor(sq[r], off, 64);

    if (row_l == 0) {
#pragma unroll
        for (int r = 0; r < 4; ++r) rsum[cg][rg * 16 + kb * 4 + r] = sq[r];
    }
    __syncthreads();  // also orders all A reads before the BF16H in-place writes

    int rbase = rg * 16 + kb * 4;
#pragma unroll
    for (int r = 0; r < 4; ++r) {
        int row = r0 + kb * 4 + r;
        if (row >= NN) continue;
        float n2 = rsum[0][rbase + r] + rsum[1][rbase + r];
        float inv = 1.0f / fmaxf(sqrtf(n2), 1e-12f);
#pragma unroll
        for (int t = 0; t < 4; ++t) {
            float v = acc[t][r] * inv;
            if (RELU) v = fmaxf(v, 0.f);
            int c = cg * 64 + t * 16 + row_l;
            if (F32OUT) outF[(size_t)row * HD + c] = v;
            if (BF16H) Hn[(size_t)row * 256 + c] = f2bf(v);
        }
    }
}

// ---------------- launch ----------------

static inline size_t align256(size_t x) { return (x + 255) & ~(size_t)255; }

extern "C" void kernel_launch(void* const* d_in, const int* in_sizes, int n_in,
                              void* d_out, int out_size, void* d_ws, size_t ws_size,
                              hipStream_t stream) {
    const float* x   = (const float*)d_in[0];
    const int*   ei  = (const int*)d_in[1];
    const float* Wl0 = (const float*)d_in[2];
    const float* bl0 = (const float*)d_in[3];
    const float* Wr0 = (const float*)d_in[4];
    const float* Wl1 = (const float*)d_in[5];
    const float* bl1 = (const float*)d_in[6];
    const float* Wr1 = (const float*)d_in[7];
    const float* Wl2 = (const float*)d_in[8];
    const float* bl2 = (const float*)d_in[9];
    const float* Wr2 = (const float*)d_in[10];

    const int* src = ei;
    const int* dst = ei + NE;

    // workspace carve-up
    char* p = (char*)d_ws;
    size_t off = 0;
    int* meta = (int*)(p + off);            off = align256(off + 512 * 4);  // bcnt[256]+bfill[256]
    int* bbase = (int*)(p + off);           off = align256(off + 256 * 4);
    int* rowptr = (int*)(p + off);          off = align256(off + (size_t)(NN + 1) * 4);
    int* csr_src = (int*)(p + off);         off = align256(off + (size_t)NE * 4);
    float* invcnt = (float*)(p + off);      off = align256(off + (size_t)NN * 4);
    int2* pairs = (int2*)(p + off);         off = align256(off + (size_t)NE * 8);
    unsigned short* A0 = (unsigned short*)(p + off);   off = align256(off + (size_t)NNP * 128 * 2);
    unsigned short* A12 = (unsigned short*)(p + off);  off = align256(off + (size_t)NNP * 256 * 2);
    unsigned short* Wpk0 = (unsigned short*)(p + off); off = align256(off + (size_t)2 * DIN * HD * 2);
    unsigned short* Wpk1 = (unsigned short*)(p + off); off = align256(off + (size_t)2 * HD * HD * 2);
    unsigned short* Wpk2 = (unsigned short*)(p + off); off = align256(off + (size_t)2 * HD * HD * 2);
    (void)ws_size; (void)n_in; (void)in_sizes; (void)out_size;

    int* bcnt = meta;
    int* bfill = meta + 256;
    float* out = (float*)d_out;

    // CSR build: two-level LDS counting sort (coalesced writes, no cross-XCD line sharing)
    zero_meta<<<1, 512, 0, stream>>>(meta);
    bucket_count<<<SB, 256, 0, stream>>>(dst, bcnt);
    bucket_scan<<<1, 256, 0, stream>>>(bcnt, bbase, rowptr);
    bucket_scatter<<<SB, 256, 0, stream>>>(src, dst, bbase, bfill, pairs);
    build_csr<<<NBUK, 256, 0, stream>>>(pairs, bbase, rowptr, invcnt, csr_src);

    // prep (independent of CSR): packed weights + dense x->bf16 into A0 h-half
    const int WTOT = 2 * DIN * HD + 2 * 2 * HD * HD;  // 81920
    pack_weights<<<(WTOT + 255) / 256, 256, 0, stream>>>(Wl0, Wr0, Wl1, Wr1, Wl2, Wr2,
                                                         Wpk0, Wpk1, Wpk2);
    conv_x<<<(NN * 16 + 255) / 256, 256, 0, stream>>>(x, A0);

    const int LG = NNP / 32;   // 1563
    const int GG = NN / 4;     // 12500 (4 nodes per block, wave per node)

    // layer 0: gather bf16 x rows -> A0 mean part; GEMM K=128 -> h0 bf16 into A12[:,128:256]
    gather_mean_x<<<GG, 256, 0, stream>>>(rowptr, csr_src, invcnt, A0);
    linear_mfma<2 * DIN, true, false, true><<<LG, 256, 0, stream>>>(
        A0, Wpk0, bl0, nullptr, A12 + 128);

    // layer 1: gather h0 (bf16) -> A12 mean part; GEMM K=256 -> h1 bf16 (in place)
    gather_mean_h<<<GG, 256, 0, stream>>>(A12, rowptr, csr_src, invcnt, A12);
    linear_mfma<2 * HD, true, false, true><<<LG, 256, 0, stream>>>(
        A12, Wpk1, bl1, nullptr, A12 + 128);

    // layer 2: gather h1 -> A12 mean part; GEMM K=256 -> f32 d_out
    gather_mean_h<<<GG, 256, 0, stream>>>(A12, rowptr, csr_src, invcnt, A12);
    linear_mfma<2 * HD, false, true, false><<<LG, 256, 0, stream>>>(
        A12, Wpk2, bl2, out, nullptr);
}